// Round 1
// baseline (301.962 us; speedup 1.0000x reference)
//
#include <hip/hip_runtime.h>

// Fully fused RotationPredHeadSim:
//  - rotation is exact 90-degree multiples -> pure index permutation gather
//  - only 8 sampled channels of z_a/z_b are touched
//  - one block per batch element (grid=32, block=256), zero workspace
__global__ __launch_bounds__(256) void rot_pred_head_fused(
    const float* __restrict__ z_a,
    const float* __restrict__ z_b,
    const float* __restrict__ cm,
    const float* __restrict__ W1,
    const float* __restrict__ b1,
    const float* __restrict__ W2,
    const float* __restrict__ b2,
    const int* __restrict__ target_l_r,
    const int* __restrict__ loc,
    float* __restrict__ out)
{
    const int b = blockIdx.x;
    const int t = threadIdx.x;

    __shared__ float m[4096];       // 64x64 downsampled (1 - rotated cm)
    __shared__ float sA[512];       // [8][64] pooled za
    __shared__ float sB[512];       // [8][64] pooled zb
    __shared__ float C[64 * 65];    // 64x64 score matrix, padded stride 65
    __shared__ float hdn[64];

    // ---- Phase 1: mask gather (rotation + nearest-downsample fused) ----
    {
        const int r = target_l_r[b];
        const float* cmb = cm + (size_t)b * 65536;
        for (int idx = t; idx < 4096; idx += 256) {
            const int y = idx >> 6, x = idx & 63;
            const int Y = y << 2, X = x << 2;
            int sy, sx;
            if (r == 0)      { sy = Y;       sx = X;       }
            else if (r == 1) { sy = 255 - X; sx = Y;       }
            else if (r == 2) { sy = 255 - Y; sx = 255 - X; }
            else             { sy = X;       sx = 255 - Y; }
            m[idx] = 1.0f - cmb[sy * 256 + sx];
        }
    }
    __syncthreads();

    // ---- Phase 2: masked 8x8 average pooling for the 8 sampled channels ----
    {
        const int cell = t >> 2;        // 0..63 : output cell (py*8+px)
        const int sub  = t & 3;         // 4 lanes cooperate per cell
        const int py = cell >> 3, px = cell & 7;
        const int row0  = py * 8 + sub * 2;      // each lane: 2 rows x 8 cols
        const int base0 = row0 * 64 + px * 8;
        const int base1 = base0 + 64;

        const float4 m00 = *(const float4*)(m + base0);
        const float4 m01 = *(const float4*)(m + base0 + 4);
        const float4 m10 = *(const float4*)(m + base1);
        const float4 m11 = *(const float4*)(m + base1 + 4);

        for (int f = 0; f < 8; ++f) {
            const size_t zoff = ((size_t)(b * 256 + loc[f])) * 4096;
            const float* pa = z_a + zoff;
            const float* pb = z_b + zoff;
            const float4 a00 = *(const float4*)(pa + base0);
            const float4 a01 = *(const float4*)(pa + base0 + 4);
            const float4 a10 = *(const float4*)(pa + base1);
            const float4 a11 = *(const float4*)(pa + base1 + 4);
            const float4 b00 = *(const float4*)(pb + base0);
            const float4 b01 = *(const float4*)(pb + base0 + 4);
            const float4 b10 = *(const float4*)(pb + base1);
            const float4 b11 = *(const float4*)(pb + base1 + 4);

            float sa = a00.x*m00.x + a00.y*m00.y + a00.z*m00.z + a00.w*m00.w
                     + a01.x*m01.x + a01.y*m01.y + a01.z*m01.z + a01.w*m01.w
                     + a10.x*m10.x + a10.y*m10.y + a10.z*m10.z + a10.w*m10.w
                     + a11.x*m11.x + a11.y*m11.y + a11.z*m11.z + a11.w*m11.w;
            float sb = b00.x*m00.x + b00.y*m00.y + b00.z*m00.z + b00.w*m00.w
                     + b01.x*m01.x + b01.y*m01.y + b01.z*m01.z + b01.w*m01.w
                     + b10.x*m10.x + b10.y*m10.y + b10.z*m10.z + b10.w*m10.w
                     + b11.x*m11.x + b11.y*m11.y + b11.z*m11.z + b11.w*m11.w;

            sa += __shfl_xor(sa, 1); sa += __shfl_xor(sa, 2);
            sb += __shfl_xor(sb, 1); sb += __shfl_xor(sb, 2);
            if (sub == 0) {
                sA[(f << 6) + cell] = sa * 0.015625f;   // /64
                sB[(f << 6) + cell] = sb * 0.015625f;
            }
        }
    }
    __syncthreads();

    // ---- Phase 3: C[i][j] = sum_f sA[f][i] * sB[f][j] ----
    for (int k = t; k < 4096; k += 256) {
        const int i = k >> 6, j = k & 63;
        float acc = 0.0f;
        #pragma unroll
        for (int f = 0; f < 8; ++f)
            acc += sA[(f << 6) + i] * sB[(f << 6) + j];
        C[i * 65 + j] = acc;
    }
    __syncthreads();

    // ---- Phase 4: softmax over i (down each column j), 4 lanes per column ----
    {
        const int j = t >> 2, sub = t & 3;
        float mx = -3.4e38f;
        for (int i = sub; i < 64; i += 4) mx = fmaxf(mx, C[i * 65 + j]);
        mx = fmaxf(mx, __shfl_xor(mx, 1));
        mx = fmaxf(mx, __shfl_xor(mx, 2));
        float s = 0.0f;
        for (int i = sub; i < 64; i += 4) {
            const float e = expf(C[i * 65 + j] - mx);
            C[i * 65 + j] = e;
            s += e;
        }
        s += __shfl_xor(s, 1);
        s += __shfl_xor(s, 2);
        const float inv = 1.0f / s;
        for (int i = sub; i < 64; i += 4) C[i * 65 + j] *= inv;
    }
    __syncthreads();

    // ---- Phase 5: hdn = relu(softC_flat @ W1^T + b1), 4 lanes per output ----
    {
        const int o = t >> 2, sub = t & 3;
        const float* w = W1 + (size_t)o * 4096;
        float acc0 = 0.f, acc1 = 0.f, acc2 = 0.f, acc3 = 0.f;
        for (int cc = sub; cc < 1024; cc += 4) {     // 1024 float4 chunks
            const int k = cc << 2;
            const int i = k >> 6, j = k & 63;        // chunk stays within row i
            const float4 wv = *(const float4*)(w + k);
            const float* cp = &C[i * 65 + j];
            acc0 += wv.x * cp[0];
            acc1 += wv.y * cp[1];
            acc2 += wv.z * cp[2];
            acc3 += wv.w * cp[3];
        }
        float acc = (acc0 + acc1) + (acc2 + acc3);
        acc += __shfl_xor(acc, 1);
        acc += __shfl_xor(acc, 2);
        if (sub == 0) hdn[o] = fmaxf(acc + b1[o], 0.0f);
    }
    __syncthreads();

    // ---- Phase 6: out = hdn @ W2^T + b2 ----
    if (t < 4) {
        float acc = b2[t];
        #pragma unroll
        for (int o = 0; o < 64; ++o) acc += hdn[o] * W2[t * 64 + o];
        out[b * 4 + t] = acc;
    }
}

extern "C" void kernel_launch(void* const* d_in, const int* in_sizes, int n_in,
                              void* d_out, int out_size, void* d_ws, size_t ws_size,
                              hipStream_t stream) {
    const float* z_a = (const float*)d_in[0];
    const float* z_b = (const float*)d_in[1];
    const float* cm  = (const float*)d_in[2];
    const float* W1  = (const float*)d_in[3];
    const float* b1  = (const float*)d_in[4];
    const float* W2  = (const float*)d_in[5];
    const float* b2  = (const float*)d_in[6];
    const int* rot   = (const int*)d_in[7];
    const int* loc   = (const int*)d_in[8];
    float* out = (float*)d_out;

    hipLaunchKernelGGL(rot_pred_head_fused, dim3(32), dim3(256), 0, stream,
                       z_a, z_b, cm, W1, b1, W2, b2, rot, loc, out);
}

// Round 2
// 241.452 us; speedup vs baseline: 1.2506x; 1.2506x over previous
//
#include <hip/hip_runtime.h>

// Two-kernel split for parallelism (R0 was 32-block latency-bound, 84 us):
//  K1: grid (32 batch x 8 feat) - masked 8x8 avg-pool, mask gathered inline
//      (rotation = exact 90-degree permutation), no LDS, no syncthreads.
//  K2: grid (32 batch x 8 o-slices) - C matrix + column softmax (redundant,
//      VALU-cheap) + W1 slice dot + partial W2 via atomicAdd.

__global__ __launch_bounds__(256) void pool_kernel(
    const float* __restrict__ z_a,
    const float* __restrict__ z_b,
    const float* __restrict__ cm,
    const int* __restrict__ target_l_r,
    const int* __restrict__ loc,
    float* __restrict__ ws)
{
    const int b = blockIdx.x;
    const int f = blockIdx.y;
    const int t = threadIdx.x;

    const int cell = t >> 2;          // 0..63 output cell (py*8+px)
    const int sub  = t & 3;           // 4 lanes per cell
    const int py = cell >> 3, px = cell & 7;
    const int row0  = py * 8 + sub * 2;      // 2 rows x 8 cols per lane
    const int base0 = row0 * 64 + px * 8;
    const int base1 = base0 + 64;

    const int r = target_l_r[b];
    const float* cmb = cm + (size_t)b * 65536;

    // inline mask gather: m[y][x] = 1 - cm_rot[4y][4x]
    float mk[16];
    #pragma unroll
    for (int i = 0; i < 16; ++i) {
        const int y = row0 + (i >> 3);
        const int x = px * 8 + (i & 7);
        const int Y = y << 2, X = x << 2;
        int sy, sx;
        if (r == 0)      { sy = Y;       sx = X;       }
        else if (r == 1) { sy = 255 - X; sx = Y;       }
        else if (r == 2) { sy = 255 - Y; sx = 255 - X; }
        else             { sy = X;       sx = 255 - Y; }
        mk[i] = 1.0f - cmb[sy * 256 + sx];
    }

    const size_t zoff = ((size_t)(b * 256 + loc[f])) * 4096;
    const float* pa = z_a + zoff;
    const float* pb = z_b + zoff;
    const float4 a00 = *(const float4*)(pa + base0);
    const float4 a01 = *(const float4*)(pa + base0 + 4);
    const float4 a10 = *(const float4*)(pa + base1);
    const float4 a11 = *(const float4*)(pa + base1 + 4);
    const float4 b00 = *(const float4*)(pb + base0);
    const float4 b01 = *(const float4*)(pb + base0 + 4);
    const float4 b10 = *(const float4*)(pb + base1);
    const float4 b11 = *(const float4*)(pb + base1 + 4);

    float sa = a00.x*mk[0] + a00.y*mk[1] + a00.z*mk[2] + a00.w*mk[3]
             + a01.x*mk[4] + a01.y*mk[5] + a01.z*mk[6] + a01.w*mk[7]
             + a10.x*mk[8] + a10.y*mk[9] + a10.z*mk[10] + a10.w*mk[11]
             + a11.x*mk[12] + a11.y*mk[13] + a11.z*mk[14] + a11.w*mk[15];
    float sb = b00.x*mk[0] + b00.y*mk[1] + b00.z*mk[2] + b00.w*mk[3]
             + b01.x*mk[4] + b01.y*mk[5] + b01.z*mk[6] + b01.w*mk[7]
             + b10.x*mk[8] + b10.y*mk[9] + b10.z*mk[10] + b10.w*mk[11]
             + b11.x*mk[12] + b11.y*mk[13] + b11.z*mk[14] + b11.w*mk[15];

    sa += __shfl_xor(sa, 1); sa += __shfl_xor(sa, 2);
    sb += __shfl_xor(sb, 1); sb += __shfl_xor(sb, 2);
    if (sub == 0) {
        const int idx = (b * 8 + f) * 64 + cell;
        ws[idx]         = sa * 0.015625f;   // pooled za, /64
        ws[16384 + idx] = sb * 0.015625f;   // pooled zb
    }
}

__global__ __launch_bounds__(256) void head_kernel(
    const float* __restrict__ ws,
    const float* __restrict__ W1,
    const float* __restrict__ b1,
    const float* __restrict__ W2,
    const float* __restrict__ b2,
    float* __restrict__ out)
{
    const int b  = blockIdx.x;
    const int og = blockIdx.y;     // output group: o = og*8 + oo
    const int t  = threadIdx.x;

    __shared__ float sA[512];      // [8][64]
    __shared__ float sB[512];
    __shared__ float C[64 * 65];   // padded stride
    __shared__ float hdn_s[8];

    // pooled features for this batch
    const float* PA = ws + (size_t)b * 512;
    const float* PB = ws + 16384 + (size_t)b * 512;
    for (int k = t; k < 512; k += 256) { sA[k] = PA[k]; sB[k] = PB[k]; }
    __syncthreads();

    // C[i][j] = sum_f sA[f][i] * sB[f][j]
    for (int k = t; k < 4096; k += 256) {
        const int i = k >> 6, j = k & 63;
        float acc = 0.0f;
        #pragma unroll
        for (int f = 0; f < 8; ++f)
            acc += sA[(f << 6) + i] * sB[(f << 6) + j];
        C[i * 65 + j] = acc;
    }
    __syncthreads();

    // softmax down each column j (4 lanes per column)
    {
        const int j = t >> 2, sub = t & 3;
        float mx = -3.4e38f;
        for (int i = sub; i < 64; i += 4) mx = fmaxf(mx, C[i * 65 + j]);
        mx = fmaxf(mx, __shfl_xor(mx, 1));
        mx = fmaxf(mx, __shfl_xor(mx, 2));
        float s = 0.0f;
        for (int i = sub; i < 64; i += 4) {
            const float e = expf(C[i * 65 + j] - mx);
            C[i * 65 + j] = e;
            s += e;
        }
        s += __shfl_xor(s, 1);
        s += __shfl_xor(s, 2);
        const float inv = 1.0f / s;
        for (int i = sub; i < 64; i += 4) C[i * 65 + j] *= inv;
    }
    __syncthreads();

    // hdn[o] = relu(dot(softC, W1[o]) + b1[o]); 32 lanes per output
    {
        const int oo = t >> 5, sub = t & 31;
        const int o  = og * 8 + oo;
        const float* w = W1 + (size_t)o * 4096;
        float acc = 0.0f;
        #pragma unroll 8
        for (int it = 0; it < 32; ++it) {
            const int k = (it * 32 + sub) << 2;      // float4-aligned, stays in row
            const int i = k >> 6, j = k & 63;
            const float4 wv = *(const float4*)(w + k);
            const float* cp = &C[i * 65 + j];
            acc += wv.x * cp[0] + wv.y * cp[1] + wv.z * cp[2] + wv.w * cp[3];
        }
        acc += __shfl_xor(acc, 1);
        acc += __shfl_xor(acc, 2);
        acc += __shfl_xor(acc, 4);
        acc += __shfl_xor(acc, 8);
        acc += __shfl_xor(acc, 16);
        if (sub == 0) hdn_s[oo] = fmaxf(acc + b1[o], 0.0f);
    }
    __syncthreads();

    // partial out: this block's 8 hdn values x W2 slice
    if (t < 4) {
        float p = 0.0f;
        #pragma unroll
        for (int q = 0; q < 8; ++q)
            p += hdn_s[q] * W2[t * 64 + og * 8 + q];
        if (og == 0) p += b2[t];
        atomicAdd(out + b * 4 + t, p);
    }
}

extern "C" void kernel_launch(void* const* d_in, const int* in_sizes, int n_in,
                              void* d_out, int out_size, void* d_ws, size_t ws_size,
                              hipStream_t stream) {
    const float* z_a = (const float*)d_in[0];
    const float* z_b = (const float*)d_in[1];
    const float* cm  = (const float*)d_in[2];
    const float* W1  = (const float*)d_in[3];
    const float* b1  = (const float*)d_in[4];
    const float* W2  = (const float*)d_in[5];
    const float* b2  = (const float*)d_in[6];
    const int* rot   = (const int*)d_in[7];
    const int* loc   = (const int*)d_in[8];
    float* out = (float*)d_out;
    float* ws  = (float*)d_ws;     // needs 32768 floats = 128 KB

    hipMemsetAsync(out, 0, (size_t)out_size * sizeof(float), stream);

    hipLaunchKernelGGL(pool_kernel, dim3(32, 8), dim3(256), 0, stream,
                       z_a, z_b, cm, rot, loc, ws);
    hipLaunchKernelGGL(head_kernel, dim3(32, 8), dim3(256), 0, stream,
                       ws, W1, b1, W2, b2, out);
}